// Round 17
// baseline (235.039 us; speedup 1.0000x reference)
//
#include <hip/hip_runtime.h>
#include <cstdint>
#include <cmath>

#define D_MODEL 256
#define NH 8
#define NLVL 4
#define LTOT 13294
#define BATCH 4
#define BTOT (BATCH * LTOT)   // 53176
#define RPAD 53248             // 208 * 256 padded rows

typedef __attribute__((ext_vector_type(8))) short bf8;
typedef __attribute__((ext_vector_type(4))) float f4;
typedef __attribute__((ext_vector_type(2))) float f2;

__device__ __forceinline__ unsigned short f2bf(float x) {
    unsigned u = __float_as_uint(x);
    u += 0x7fffu + ((u >> 16) & 1u);      // round-to-nearest-even
    return (unsigned short)(u >> 16);
}
__device__ __forceinline__ float bf2f(unsigned short h) {
    return __uint_as_float(((unsigned)h) << 16);
}
// unpack dword of 2 bf16 -> f2 {lo, hi}
__device__ __forceinline__ f2 up2(unsigned u) {
    return (f2){__uint_as_float(u << 16), __uint_as_float(u & 0xffff0000u)};
}
// chunk-slot swizzle: slot s of row i holds k-octet s ^ ((i>>1)&3)
__device__ __forceinline__ int swzf(int i, int s) { return s ^ ((i >> 1) & 3); }
// bijective XCD swizzle (m204): consecutive logical ids stay on one XCD
__device__ __forceinline__ int xcd_swz(int hw, int nwg) {
    int xcd = hw & 7, k = hw >> 3;
    int q = nwg >> 3, r = nwg & 7;
    return (xcd < r ? xcd * (q + 1) : r * (q + 1) + (xcd - r) * q) + k;
}

// levels: (100,100),(50,50),(25,25),(13,13); offsets 0,10000,12500,13125
__device__ __forceinline__ void level_of(int l, int& lv, int& hw, int& Wl, int& HWl, int& loff) {
    if (l < 10000)      { lv = 0; loff = 0;     Wl = 100; HWl = 10000; }
    else if (l < 12500) { lv = 1; loff = 10000; Wl = 50;  HWl = 2500;  }
    else if (l < 13125) { lv = 2; loff = 12500; Wl = 25;  HWl = 625;   }
    else                { lv = 3; loff = 13125; Wl = 13;  HWl = 169;   }
    hw = l - loff;
}

#define NCONV (RPAD / 64)       // 832 convert blocks
#define NPACK 96                // weight-pack blocks
#define NGEO  208               // geometry-table blocks (208*256 >= BTOT)

// ---------------------------------------------------------------- convert A + pack weights + geo table (merged)
__global__ __launch_bounds__(256) void convert_pack(
    const float* __restrict__ v0, const float* __restrict__ v1,
    const float* __restrict__ v2, const float* __restrict__ v3,
    const float* __restrict__ p0, const float* __restrict__ p1,
    const float* __restrict__ p2, const float* __restrict__ p3,
    const float* __restrict__ Wv, const float* __restrict__ Wattn,
    const float* __restrict__ Wbox, const float* __restrict__ Wo,
    unsigned short* __restrict__ Gv, unsigned short* __restrict__ Gq,
    unsigned short* __restrict__ W1hi, unsigned short* __restrict__ W1lo,
    unsigned short* __restrict__ Wohi, unsigned short* __restrict__ Wolo,
    float4* __restrict__ geot) {
    __shared__ unsigned short HV[64][130];
    __shared__ unsigned short HQ[64][130];
    int t = threadIdx.x;

    if (blockIdx.x >= NCONV) {
        if (blockIdx.x >= NCONV + NPACK) {
            // ---- geometry table path: geo[r] = {cx, cy, rsw, rb0}
            int rr = (blockIdx.x - (NCONV + NPACK)) * 256 + t;
            if (rr < BTOT) {
                int l = rr % LTOT;
                int lv, hw, Wl, HWl, loff;
                level_of(l, lv, hw, Wl, HWl, loff);
                int x, y;
                switch (lv) {
                    case 0:  y = hw / 100; x = hw - y * 100; break;
                    case 1:  y = hw / 50;  x = hw - y * 50;  break;
                    case 2:  y = hw / 25;  x = hw - y * 25;  break;
                    default: y = hw / 13;  x = hw - y * 13;  break;
                }
                float denom = (float)((double)Wl + 1e-6);
                float4 g;
                g.x = ((float)x + 0.5f) / denom;
                g.y = ((float)y + 0.5f) / denom;
                g.z = 4.0f / (float)Wl;
                g.w = __int_as_float(rr - l);     // rb0 = b*LTOT
                geot[rr] = g;
            }
            return;
        }
        // ---- pack weights path
        int tid = (blockIdx.x - NCONV) * 256 + t;
        const float* src;
        unsigned short *dh, *dl;
        int nb, kb, j, s;
        if (tid < 16384) {                       // GEMM1 B: 4 nb x 8 kb x 128 j x 4 s
            nb = tid >> 12; kb = (tid >> 9) & 7; j = (tid >> 2) & 127; s = tid & 3;
            int f = nb * 128 + j, c0 = kb * 32 + s * 8;
            if (f < 256)      src = Wv + (size_t)f * 256 + c0;
            else if (f < 384) src = Wattn + (size_t)(f - 256) * 256 + c0;
            else              src = Wbox + (size_t)(f - 384) * 256 + c0;
            dh = W1hi; dl = W1lo;
        } else {                                 // GEMM2 B: 2 nb x 8 kb x 128 j x 4 s
            int t2 = tid - 16384;
            nb = t2 >> 12; kb = (t2 >> 9) & 7; j = (t2 >> 2) & 127; s = t2 & 3;
            int f = nb * 128 + j, c0 = kb * 32 + s * 8;
            src = Wo + (size_t)f * 256 + c0;
            dh = Wohi; dl = Wolo;
        }
        int base = (((nb * 8 + kb) * 128 + j) * 4 + swzf(j, s)) * 8;
        #pragma unroll
        for (int e = 0; e < 8; ++e) {
            float x = src[e];
            unsigned short h = f2bf(x);
            dh[base + e] = h;
            dl[base + e] = f2bf(x - bf2f(h));
        }
        return;
    }

    // ---- convert A path
    int w = t >> 6, lane = t & 63;
    int r0 = blockIdx.x * 64;

    int r = r0 + lane; if (r >= BTOT) r = BTOT - 1;
    int b = r / LTOT, l = r % LTOT;
    int lv, hw, Wl, HWl, loff;
    level_of(l, lv, hw, Wl, HWl, loff);
    const float *vb, *pb;
    switch (lv) { case 0: vb = v0; pb = p0; break; case 1: vb = v1; pb = p1; break;
                  case 2: vb = v2; pb = p2; break; default: vb = v3; pb = p3; break; }
    size_t base = (size_t)b * D_MODEL * (size_t)HWl + (size_t)hw;
    vb += base; pb += base;

    int kb2 = (lane >> 2) & 3, slot = lane & 3;
    for (int h = 0; h < 2; ++h) {
        #pragma unroll 4
        for (int i = 0; i < 32; ++i) {
            int cl = i * 4 + w;
            int c = h * 128 + cl;
            float av = vb[(size_t)c * HWl];
            float aq = av + pb[(size_t)c * HWl];
            HV[lane][cl] = f2bf(av);
            HQ[lane][cl] = f2bf(aq);
        }
        __syncthreads();
        #pragma unroll
        for (int j = 0; j < 8; ++j) {
            int plane = j >> 2;
            int rl = (j & 3) * 16 + w * 4 + (lane >> 4);
            int oct = slot ^ ((rl >> 1) & 3);
            const unsigned* s32 = (const unsigned*)(plane ? &HQ[rl][kb2 * 32 + oct * 8]
                                                          : &HV[rl][kb2 * 32 + oct * 8]);
            uint4 vst = make_uint4(s32[0], s32[1], s32[2], s32[3]);
            unsigned short* dst = (plane ? Gq : Gv)
                + (size_t)(r0 + rl) * 256 + (h * 4 + kb2) * 32 + slot * 8;
            *(uint4*)dst = vst;
        }
        __syncthreads();
    }
}

// ---------------------------------------------------------------- GEMM1 (MFMA)
// 256x128 tile, 512 threads (8 waves, 4x2), A double-buffered in LDS (32 KB),
// B-fragments read DIRECTLY from prepacked global (L2-resident, barrier-free).
__global__ __launch_bounds__(512, 3) void gemm1_mfma(
    const unsigned short* __restrict__ Gv, const unsigned short* __restrict__ Gq,
    const unsigned short* __restrict__ W1hi, const unsigned short* __restrict__ W1lo,
    const float* __restrict__ bv, const float* __restrict__ battn, const float* __restrict__ bbox,
    unsigned short* __restrict__ VPb, float* __restrict__ LB) {
    __shared__ __align__(16) unsigned short Ah[2][8192];   // 32 KB
    int t = threadIdx.x;
    int lid = xcd_swz(blockIdx.x, 4 * (RPAD / 256));   // 832 blocks
    int nb = lid & 3;                    // 0..3
    int r0 = (lid >> 2) * 256;
    const unsigned short* Asrc = (nb < 2) ? Gv : Gq;
    int w = t >> 6, lane = t & 63;
    int wr = w >> 1, wc = w & 1;         // 4x2 wave grid
    int row_l = lane & 15, oct = lane >> 4;

    // B direct-frag pointers (swizzle-compensated prepack offsets), kb adds 4096
    const unsigned short* pbh[4];
    const unsigned short* pbl[4];
    #pragma unroll
    for (int x = 0; x < 4; ++x) {
        int ci = wc * 64 + x * 16 + row_l;
        int off = (ci * 4 + swzf(ci, oct)) * 8;
        pbh[x] = W1hi + (size_t)nb * 32768 + off;
        pbl[x] = W1lo + (size_t)nb * 32768 + off;
    }

    f4 acc[4][4];
    #pragma unroll
    for (int i = 0; i < 4; ++i)
        #pragma unroll
        for (int j = 0; j < 4; ++j) acc[i][j] = (f4){0.f, 0.f, 0.f, 0.f};

    int c0 = t, c1 = t + 512;
    const unsigned short* a0b = Asrc + (size_t)(r0 + (c0 >> 2)) * 256 + (c0 & 3) * 8;
    const unsigned short* a1b = Asrc + (size_t)(r0 + (c1 >> 2)) * 256 + (c1 & 3) * 8;

#define G1_STAGE(bb, kb)                                                            \
    {                                                                               \
        __builtin_amdgcn_global_load_lds(a0b + (kb) * 32, &Ah[bb][w * 512], 16, 0, 0);        \
        __builtin_amdgcn_global_load_lds(a1b + (kb) * 32, &Ah[bb][4096 + w * 512], 16, 0, 0); \
    }

    G1_STAGE(0, 0);
    for (int kb = 0; kb < 8; ++kb) {
        __syncthreads();                       // drains prefetch; buf kb ready
        if (kb < 7) G1_STAGE((kb + 1) & 1, kb + 1);
        int bb = kb & 1;
        bf8 a[4], bh[4], bl[4];
        #pragma unroll
        for (int x = 0; x < 4; ++x) {
            bh[x] = *(const bf8*)(pbh[x] + kb * 4096);
            bl[x] = *(const bf8*)(pbl[x] + kb * 4096);
        }
        #pragma unroll
        for (int x = 0; x < 4; ++x) {
            int ri = wr * 64 + x * 16 + row_l;     // 0..255
            a[x] = *(const bf8*)(&Ah[bb][ri * 32 + swzf(ri, oct) * 8]);
        }
        #pragma unroll
        for (int mi = 0; mi < 4; ++mi)
            #pragma unroll
            for (int ni = 0; ni < 4; ++ni) {
                f4 c = acc[mi][ni];
                c = __builtin_amdgcn_mfma_f32_16x16x32_bf16(a[mi], bh[ni], c, 0, 0, 0);
                c = __builtin_amdgcn_mfma_f32_16x16x32_bf16(a[mi], bl[ni], c, 0, 0, 0);
                acc[mi][ni] = c;
            }
    }
    #pragma unroll
    for (int ni = 0; ni < 4; ++ni) {
        int col = wc * 64 + ni * 16 + row_l;
        float bias;
        if (nb == 0) bias = bv[col];
        else if (nb == 1) bias = bv[128 + col];
        else if (nb == 2) bias = battn[col];
        else bias = bbox[col];
        #pragma unroll
        for (int mi = 0; mi < 4; ++mi) {
            #pragma unroll
            for (int v = 0; v < 4; ++v) {
                int rr = r0 + wr * 64 + mi * 16 + oct * 4 + v;
                if (rr < BTOT) {
                    float val = acc[mi][ni][v] + bias;
                    if (nb < 2) VPb[(size_t)rr * 256 + nb * 128 + col] = f2bf(val);
                    else        LB[(size_t)rr * 256 + (nb - 2) * 128 + col] = val;
                }
            }
        }
    }
}

// ---------------------------------------------------------------- sampler v12
// 256 thr = 64 groups, 4 lanes/group (lane = level). Register-resident phase 1,
// width-4 shuffle broadcast phase 2, dwordx4 bf16 gathers + packed f32 fma.
__global__ __launch_bounds__(256) void sampler_kernel(const unsigned short* __restrict__ VPb,
                                                      const float* __restrict__ LB,
                                                      const float4* __restrict__ geot,
                                                      unsigned short* __restrict__ att_hi,
                                                      unsigned short* __restrict__ att_lo) {
    int t = threadIdx.x;
    int blk = xcd_swz(blockIdx.x, (BTOT * NH) / 64);   // 6647 blocks
    int gidx = t >> 2, lane4 = t & 3;                  // lane4 = level
    int grp = blk * 64 + gidx;
    int m = grp & 7, r = grp >> 3;

    float4 gt = geot[r];
    float cx = gt.x, cy = gt.y, rsw = gt.z;
    int rb0 = __float_as_int(gt.w);

    const float* Lrow = LB + (size_t)r * 256;
    float4 lg4 = *(const float4*)&Lrow[m * 16 + lane4 * 4];
    float4 ob  = *(const float4*)&Lrow[128 + m * 16 + lane4 * 4];

    float mx = fmaxf(fmaxf(lg4.x, lg4.y), fmaxf(lg4.z, lg4.w));
    mx = fmaxf(mx, __shfl_xor(mx, 1, 4));
    mx = fmaxf(mx, __shfl_xor(mx, 2, 4));
    float e0 = __expf(lg4.x - mx), e1 = __expf(lg4.y - mx);
    float e2 = __expf(lg4.z - mx), e3 = __expf(lg4.w - mx);
    float s = (e0 + e1) + (e2 + e3);
    s += __shfl_xor(s, 1, 4);
    s += __shfl_xor(s, 2, 4);
    float inv = 1.0f / s;

    float fW2 = lane4 == 0 ? 100.f : lane4 == 1 ? 50.f : lane4 == 2 ? 25.f : 13.f;
    int   W2i = lane4 == 0 ? 100   : lane4 == 1 ? 50   : lane4 == 2 ? 25   : 13;
    int  rowb = rb0 + (lane4 == 0 ? 0 : lane4 == 1 ? 10000 : lane4 == 2 ? 12500 : 13125);
    int  col  = m * 32;

    float bcx = cx + ob.x * 0.125f * rsw;
    float bcy = cy + ob.y * 0.125f * rsw;
    float bsx = fmaxf(fmaf(ob.z * 0.125f, rsw, rsw), 0.f);
    float bsy = fmaxf(fmaf(ob.w * 0.125f, rsw, rsw), 0.f);

    float4 wA[4]; int4 iA[4];
    float ev[4] = {e0, e1, e2, e3};
    #pragma unroll
    for (int pp = 0; pp < 4; ++pp) {
        float aw = ev[pp] * inv;
        float kx = (pp & 1)  ? 0.25f : -0.25f;
        float ky = (pp >> 1) ? 0.25f : -0.25f;
        float xs = fmaf(bcx + kx * bsx, fW2, -0.5f);
        float ys = fmaf(bcy + ky * bsy, fW2, -0.5f);
        float x0f = floorf(xs), y0f = floorf(ys);
        float lx = xs - x0f, ly = ys - y0f;
        int x0 = (int)x0f, y0 = (int)y0f;
        int x1 = x0 + 1, y1 = y0 + 1;
        bool vx0 = (x0 >= 0) & (x0 < W2i), vx1 = (x1 >= 0) & (x1 < W2i);
        bool vy0 = (y0 >= 0) & (y0 < W2i), vy1 = (y1 >= 0) & (y1 < W2i);
        int x0c = min(max(x0, 0), W2i - 1), x1c = min(max(x1, 0), W2i - 1);
        int y0c = min(max(y0, 0), W2i - 1), y1c = min(max(y1, 0), W2i - 1);
        wA[pp].x = (vx0 & vy0) ? aw * (1.f - lx) * (1.f - ly) : 0.f;
        wA[pp].y = (vx1 & vy0) ? aw * lx * (1.f - ly) : 0.f;
        wA[pp].z = (vx0 & vy1) ? aw * (1.f - lx) * ly : 0.f;
        wA[pp].w = (vx1 & vy1) ? aw * lx * ly : 0.f;
        iA[pp].x = ((rowb + y0c * W2i + x0c) * 256 + col) * 2;   // BYTE offsets
        iA[pp].y = ((rowb + y0c * W2i + x1c) * 256 + col) * 2;
        iA[pp].z = ((rowb + y1c * W2i + x0c) * 256 + col) * 2;
        iA[pp].w = ((rowb + y1c * W2i + x1c) * 256 + col) * 2;
    }

    unsigned dby = (unsigned)lane4 * 16u;          // 8 channels x 2B
    const char* Vb = (const char*)VPb;
    f2 a01 = {0.f, 0.f}, a23 = {0.f, 0.f}, a45 = {0.f, 0.f}, a67 = {0.f, 0.f};

#define PSTEP(P)                                                                      \
    {                                                                                 \
        float w00 = __shfl(wA[(P) & 3].x, (P) >> 2, 4);                               \
        float w01 = __shfl(wA[(P) & 3].y, (P) >> 2, 4);                               \
        float w10 = __shfl(wA[(P) & 3].z, (P) >> 2, 4);                               \
        float w11 = __shfl(wA[(P) & 3].w, (P) >> 2, 4);                               \
        unsigned o00 = (unsigned)__shfl(iA[(P) & 3].x, (P) >> 2, 4) + dby;            \
        unsigned o01 = (unsigned)__shfl(iA[(P) & 3].y, (P) >> 2, 4) + dby;            \
        unsigned o10 = (unsigned)__shfl(iA[(P) & 3].z, (P) >> 2, 4) + dby;            \
        unsigned o11 = (unsigned)__shfl(iA[(P) & 3].w, (P) >> 2, 4) + dby;            \
        uint4 u00 = *(const uint4*)(Vb + (size_t)o00);                                \
        uint4 u01 = *(const uint4*)(Vb + (size_t)o01);                                \
        uint4 u10 = *(const uint4*)(Vb + (size_t)o10);                                \
        uint4 u11 = *(const uint4*)(Vb + (size_t)o11);                                \
        f2 ww0 = {w00, w00}, ww1 = {w01, w01}, ww2 = {w10, w10}, ww3 = {w11, w11};    \
        a01 = __builtin_elementwise_fma(ww0, up2(u00.x), a01);                        \
        a23 = __builtin_elementwise_fma(ww0, up2(u00.y), a23);                        \
        a45 = __builtin_elementwise_fma(ww0, up2(u00.z), a45);                        \
        a67 = __builtin_elementwise_fma(ww0, up2(u00.w), a67);                        \
        a01 = __builtin_elementwise_fma(ww1, up2(u01.x), a01);                        \
        a23 = __builtin_elementwise_fma(ww1, up2(u01.y), a23);                        \
        a45 = __builtin_elementwise_fma(ww1, up2(u01.z), a45);                        \
        a67 = __builtin_elementwise_fma(ww1, up2(u01.w), a67);                        \
        a01 = __builtin_elementwise_fma(ww2, up2(u10.x), a01);                        \
        a23 = __builtin_elementwise_fma(ww2, up2(u10.y), a23);                        \
        a45 = __builtin_elementwise_fma(ww2, up2(u10.z), a45);                        \
        a67 = __builtin_elementwise_fma(ww2, up2(u10.w), a67);                        \
        a01 = __builtin_elementwise_fma(ww3, up2(u11.x), a01);                        \
        a23 = __builtin_elementwise_fma(ww3, up2(u11.y), a23);                        \
        a45 = __builtin_elementwise_fma(ww3, up2(u11.z), a45);                        \
        a67 = __builtin_elementwise_fma(ww3, up2(u11.w), a67);                        \
    }

    PSTEP(0)  PSTEP(1)  PSTEP(2)  PSTEP(3)
    PSTEP(4)  PSTEP(5)  PSTEP(6)  PSTEP(7)
    PSTEP(8)  PSTEP(9)  PSTEP(10) PSTEP(11)
    PSTEP(12) PSTEP(13) PSTEP(14) PSTEP(15)
#undef PSTEP

    // 8 channels = one full octet; baked swizzle for GEMM2 A staging
    int slot = lane4 ^ ((r >> 1) & 3);
    size_t base = (size_t)r * 256 + m * 32 + slot * 8;
    float av[8] = {a01.x, a01.y, a23.x, a23.y, a45.x, a45.y, a67.x, a67.y};
    unsigned hp[4], lp4[4];
    #pragma unroll
    for (int q = 0; q < 4; ++q) {
        unsigned short h0 = f2bf(av[q * 2]), h1 = f2bf(av[q * 2 + 1]);
        unsigned short l0 = f2bf(av[q * 2] - bf2f(h0)), l1 = f2bf(av[q * 2 + 1] - bf2f(h1));
        hp[q]  = ((unsigned)h1 << 16) | h0;
        lp4[q] = ((unsigned)l1 << 16) | l0;
    }
    *(uint4*)&att_hi[base] = make_uint4(hp[0], hp[1], hp[2], hp[3]);
    *(uint4*)&att_lo[base] = make_uint4(lp4[0], lp4[1], lp4[2], lp4[3]);
}

// ---------------------------------------------------------------- GEMM2 (MFMA)
// 256x128 tile, 512 threads (8 waves, 4x2), A hi/lo double-buffered in LDS
// (64 KB), B-fragments read directly from prepacked global (L2-resident).
__global__ __launch_bounds__(512, 2) void gemm2_mfma(
    const unsigned short* __restrict__ Ahi_g, const unsigned short* __restrict__ Alo_g,
    const unsigned short* __restrict__ Wohi, const unsigned short* __restrict__ Wolo,
    const float* __restrict__ bo, float* __restrict__ out) {
    __shared__ __align__(16) unsigned short Ah[2][8192], Al[2][8192];   // 64 KB
    int t = threadIdx.x;
    int lid = xcd_swz(blockIdx.x, 2 * (RPAD / 256));   // 416 blocks
    int nb = lid & 1;                    // 0..1
    int r0 = (lid >> 1) * 256;
    int w = t >> 6, lane = t & 63;
    int wr = w >> 1, wc = w & 1;         // 4x2 wave grid
    int row_l = lane & 15, oct = lane >> 4;

    const unsigned short* pbh[4];
    const unsigned short* pbl[4];
    #pragma unroll
    for (int x = 0; x < 4; ++x) {
        int ci = wc * 64 + x * 16 + row_l;
        int off = (ci * 4 + swzf(ci, oct)) * 8;
        pbh[x] = Wohi + (size_t)nb * 32768 + off;
        pbl[x] = Wolo + (size_t)nb * 32768 + off;
    }

    f4 acc[4][4];
    #pragma unroll
    for (int i = 0; i < 4; ++i)
        #pragma unroll
        for (int j = 0; j < 4; ++j) acc[i][j] = (f4){0.f, 0.f, 0.f, 0.f};

    int c0 = t, c1 = t + 512;
    int ra0 = r0 + (c0 >> 2); if (ra0 >= BTOT) ra0 = BTOT - 1;
    int ra1 = r0 + (c1 >> 2); if (ra1 >= BTOT) ra1 = BTOT - 1;
    const unsigned short* ah0 = Ahi_g + (size_t)ra0 * 256 + (c0 & 3) * 8;
    const unsigned short* ah1 = Ahi_g + (size_t)ra1 * 256 + (c1 & 3) * 8;
    const unsigned short* al0 = Alo_g + (size_t)ra0 * 256 + (c0 & 3) * 8;
    const unsigned short* al1 = Alo_g + (size_t)ra1 * 256 + (c1 & 3) * 8;

#define G2_STAGE(bb, kb)                                                            \
    {                                                                               \
        __builtin_amdgcn_global_load_lds(ah0 + (kb) * 32, &Ah[bb][w * 512], 16, 0, 0);        \
        __builtin_amdgcn_global_load_lds(ah1 + (kb) * 32, &Ah[bb][4096 + w * 512], 16, 0, 0); \
        __builtin_amdgcn_global_load_lds(al0 + (kb) * 32, &Al[bb][w * 512], 16, 0, 0);        \
        __builtin_amdgcn_global_load_lds(al1 + (kb) * 32, &Al[bb][4096 + w * 512], 16, 0, 0); \
    }

    G2_STAGE(0, 0);
    for (int kb = 0; kb < 8; ++kb) {
        __syncthreads();
        if (kb < 7) G2_STAGE((kb + 1) & 1, kb + 1);
        int bb = kb & 1;
        bf8 ah[4], al[4], bh[4], bl[4];
        #pragma unroll
        for (int x = 0; x < 4; ++x) {
            bh[x] = *(const bf8*)(pbh[x] + kb * 4096);
            bl[x] = *(const bf8*)(pbl[x] + kb * 4096);
        }
        #pragma unroll
        for (int x = 0; x < 4; ++x) {
            int ri = wr * 64 + x * 16 + row_l;     // 0..255
            ah[x] = *(const bf8*)(&Ah[bb][ri * 32 + swzf(ri, oct) * 8]);
            al[x] = *(const bf8*)(&Al[bb][ri * 32 + swzf(ri, oct) * 8]);
        }
        #pragma unroll
        for (int mi = 0; mi < 4; ++mi)
            #pragma unroll
            for (int ni = 0; ni < 4; ++ni) {
                f4 c = acc[mi][ni];
                c = __builtin_amdgcn_mfma_f32_16x16x32_bf16(ah[mi], bh[ni], c, 0, 0, 0);
                c = __builtin_amdgcn_mfma_f32_16x16x32_bf16(ah[mi], bl[ni], c, 0, 0, 0);
                c = __builtin_amdgcn_mfma_f32_16x16x32_bf16(al[mi], bh[ni], c, 0, 0, 0);
                acc[mi][ni] = c;
            }
    }
    #pragma unroll
    for (int ni = 0; ni < 4; ++ni) {
        int col = wc * 64 + ni * 16 + row_l;
        float bias = bo[nb * 128 + col];
        #pragma unroll
        for (int mi = 0; mi < 4; ++mi) {
            #pragma unroll
            for (int v = 0; v < 4; ++v) {
                int rr = r0 + wr * 64 + mi * 16 + oct * 4 + v;
                if (rr < BTOT)
                    out[(size_t)rr * 256 + nb * 128 + col] = acc[mi][ni][v] + bias;
            }
        }
    }
}

// ---------------------------------------------------------------- launch
extern "C" void kernel_launch(void* const* d_in, const int* in_sizes, int n_in,
                              void* d_out, int out_size, void* d_ws, size_t ws_size,
                              hipStream_t stream) {
    const float* v0 = (const float*)d_in[0];
    const float* p0 = (const float*)d_in[1];
    const float* v1 = (const float*)d_in[2];
    const float* p1 = (const float*)d_in[3];
    const float* v2 = (const float*)d_in[4];
    const float* p2 = (const float*)d_in[5];
    const float* v3 = (const float*)d_in[6];
    const float* p3 = (const float*)d_in[7];
    const float* Wv    = (const float*)d_in[8];
    const float* bv    = (const float*)d_in[9];
    const float* Wo    = (const float*)d_in[10];
    const float* bo    = (const float*)d_in[11];
    const float* Wbox  = (const float*)d_in[12];
    const float* bbox  = (const float*)d_in[13];
    const float* Wattn = (const float*)d_in[14];
    const float* battn = (const float*)d_in[15];
    float* out = (float*)d_out;

    char* ws = (char*)d_ws;
    unsigned short* W1hi = (unsigned short*)(ws);                  // 256KB
    unsigned short* W1lo = (unsigned short*)(ws + 262144);         // 256KB
    unsigned short* Wohi = (unsigned short*)(ws + 524288);         // 128KB
    unsigned short* Wolo = (unsigned short*)(ws + 655360);         // 128KB
    // A panels (27.26MB each); atth/attl alias them (dead after gemm1)
    unsigned short* Gv   = (unsigned short*)(ws + 1048576);
    unsigned short* Gq   = (unsigned short*)(ws + 1048576 + 27262976);
    unsigned short* atth = Gv;
    unsigned short* attl = Gq;
    unsigned short* VPb  = (unsigned short*)(ws + 1048576 + 2 * 27262976);          // 27.23MB
    float*          LB   = (float*)(ws + 1048576 + 2 * 27262976 + 27226112);        // 54.45MB
    float4*         geot = (float4*)(ws + 1048576 + 2 * 27262976 + 27226112 + 54452224);  // 852KB

    convert_pack<<<dim3(NCONV + NPACK + NGEO), dim3(256), 0, stream>>>(
        v0, v1, v2, v3, p0, p1, p2, p3, Wv, Wattn, Wbox, Wo,
        Gv, Gq, W1hi, W1lo, Wohi, Wolo, geot);

    gemm1_mfma<<<dim3(4 * (RPAD / 256)), dim3(512), 0, stream>>>(
        Gv, Gq, W1hi, W1lo, bv, battn, bbox, VPb, LB);

    sampler_kernel<<<dim3((BTOT * NH) / 64), dim3(256), 0, stream>>>(VPb, LB, geot, atth, attl);

    gemm2_mfma<<<dim3(2 * (RPAD / 256)), dim3(512), 0, stream>>>(
        atth, attl, Wohi, Wolo, bo, out);
}

// Round 18
// 208.739 us; speedup vs baseline: 1.1260x; 1.1260x over previous
//
#include <hip/hip_runtime.h>
#include <cstdint>
#include <cmath>

#define D_MODEL 256
#define NH 8
#define NLVL 4
#define LTOT 13294
#define BATCH 4
#define BTOT (BATCH * LTOT)   // 53176
#define RPAD 53248             // 208 * 256 padded rows

typedef __attribute__((ext_vector_type(8))) short bf8;
typedef __attribute__((ext_vector_type(4))) float f4;
typedef __attribute__((ext_vector_type(2))) float f2;

__device__ __forceinline__ unsigned short f2bf(float x) {
    unsigned u = __float_as_uint(x);
    u += 0x7fffu + ((u >> 16) & 1u);      // round-to-nearest-even
    return (unsigned short)(u >> 16);
}
__device__ __forceinline__ float bf2f(unsigned short h) {
    return __uint_as_float(((unsigned)h) << 16);
}
// unpack dword of 2 bf16 -> f2 {lo, hi}
__device__ __forceinline__ f2 up2(unsigned u) {
    return (f2){__uint_as_float(u << 16), __uint_as_float(u & 0xffff0000u)};
}
// chunk-slot swizzle: slot s of row i holds k-octet s ^ ((i>>1)&3)
__device__ __forceinline__ int swzf(int i, int s) { return s ^ ((i >> 1) & 3); }
// bijective XCD swizzle (m204): consecutive logical ids stay on one XCD
__device__ __forceinline__ int xcd_swz(int hw, int nwg) {
    int xcd = hw & 7, k = hw >> 3;
    int q = nwg >> 3, r = nwg & 7;
    return (xcd < r ? xcd * (q + 1) : r * (q + 1) + (xcd - r) * q) + k;
}

// levels: (100,100),(50,50),(25,25),(13,13); offsets 0,10000,12500,13125
__device__ __forceinline__ void level_of(int l, int& lv, int& hw, int& Wl, int& HWl, int& loff) {
    if (l < 10000)      { lv = 0; loff = 0;     Wl = 100; HWl = 10000; }
    else if (l < 12500) { lv = 1; loff = 10000; Wl = 50;  HWl = 2500;  }
    else if (l < 13125) { lv = 2; loff = 12500; Wl = 25;  HWl = 625;   }
    else                { lv = 3; loff = 13125; Wl = 13;  HWl = 169;   }
    hw = l - loff;
}

#define NCONV (RPAD / 64)       // 832 convert blocks
#define NPACK 96                // weight-pack blocks
#define NGEO  208               // geometry-table blocks (208*256 >= BTOT)

// ---------------------------------------------------------------- convert A + pack weights + geo table (merged)
__global__ __launch_bounds__(256) void convert_pack(
    const float* __restrict__ v0, const float* __restrict__ v1,
    const float* __restrict__ v2, const float* __restrict__ v3,
    const float* __restrict__ p0, const float* __restrict__ p1,
    const float* __restrict__ p2, const float* __restrict__ p3,
    const float* __restrict__ Wv, const float* __restrict__ Wattn,
    const float* __restrict__ Wbox, const float* __restrict__ Wo,
    unsigned short* __restrict__ Gv, unsigned short* __restrict__ Gq,
    unsigned short* __restrict__ W1hi, unsigned short* __restrict__ W1lo,
    unsigned short* __restrict__ Wohi, unsigned short* __restrict__ Wolo,
    float4* __restrict__ geot) {
    __shared__ unsigned short HV[64][130];
    __shared__ unsigned short HQ[64][130];
    int t = threadIdx.x;

    if (blockIdx.x >= NCONV) {
        if (blockIdx.x >= NCONV + NPACK) {
            // ---- geometry table path: geo[r] = {cx, cy, rsw, rb0}
            int rr = (blockIdx.x - (NCONV + NPACK)) * 256 + t;
            if (rr < BTOT) {
                int l = rr % LTOT;
                int lv, hw, Wl, HWl, loff;
                level_of(l, lv, hw, Wl, HWl, loff);
                int x, y;
                switch (lv) {
                    case 0:  y = hw / 100; x = hw - y * 100; break;
                    case 1:  y = hw / 50;  x = hw - y * 50;  break;
                    case 2:  y = hw / 25;  x = hw - y * 25;  break;
                    default: y = hw / 13;  x = hw - y * 13;  break;
                }
                float denom = (float)((double)Wl + 1e-6);
                float4 g;
                g.x = ((float)x + 0.5f) / denom;
                g.y = ((float)y + 0.5f) / denom;
                g.z = 4.0f / (float)Wl;
                g.w = __int_as_float(rr - l);     // rb0 = b*LTOT
                geot[rr] = g;
            }
            return;
        }
        // ---- pack weights path
        int tid = (blockIdx.x - NCONV) * 256 + t;
        const float* src;
        unsigned short *dh, *dl;
        int nb, kb, j, s;
        if (tid < 16384) {                       // GEMM1 B: 4 nb x 8 kb x 128 j x 4 s
            nb = tid >> 12; kb = (tid >> 9) & 7; j = (tid >> 2) & 127; s = tid & 3;
            int f = nb * 128 + j, c0 = kb * 32 + s * 8;
            if (f < 256)      src = Wv + (size_t)f * 256 + c0;
            else if (f < 384) src = Wattn + (size_t)(f - 256) * 256 + c0;
            else              src = Wbox + (size_t)(f - 384) * 256 + c0;
            dh = W1hi; dl = W1lo;
        } else {                                 // GEMM2 B: 2 nb x 8 kb x 128 j x 4 s
            int t2 = tid - 16384;
            nb = t2 >> 12; kb = (t2 >> 9) & 7; j = (t2 >> 2) & 127; s = t2 & 3;
            int f = nb * 128 + j, c0 = kb * 32 + s * 8;
            src = Wo + (size_t)f * 256 + c0;
            dh = Wohi; dl = Wolo;
        }
        int base = (((nb * 8 + kb) * 128 + j) * 4 + swzf(j, s)) * 8;
        #pragma unroll
        for (int e = 0; e < 8; ++e) {
            float x = src[e];
            unsigned short h = f2bf(x);
            dh[base + e] = h;
            dl[base + e] = f2bf(x - bf2f(h));
        }
        return;
    }

    // ---- convert A path
    int w = t >> 6, lane = t & 63;
    int r0 = blockIdx.x * 64;

    int r = r0 + lane; if (r >= BTOT) r = BTOT - 1;
    int b = r / LTOT, l = r % LTOT;
    int lv, hw, Wl, HWl, loff;
    level_of(l, lv, hw, Wl, HWl, loff);
    const float *vb, *pb;
    switch (lv) { case 0: vb = v0; pb = p0; break; case 1: vb = v1; pb = p1; break;
                  case 2: vb = v2; pb = p2; break; default: vb = v3; pb = p3; break; }
    size_t base = (size_t)b * D_MODEL * (size_t)HWl + (size_t)hw;
    vb += base; pb += base;

    int kb2 = (lane >> 2) & 3, slot = lane & 3;
    for (int h = 0; h < 2; ++h) {
        #pragma unroll 4
        for (int i = 0; i < 32; ++i) {
            int cl = i * 4 + w;
            int c = h * 128 + cl;
            float av = vb[(size_t)c * HWl];
            float aq = av + pb[(size_t)c * HWl];
            HV[lane][cl] = f2bf(av);
            HQ[lane][cl] = f2bf(aq);
        }
        __syncthreads();
        #pragma unroll
        for (int j = 0; j < 8; ++j) {
            int plane = j >> 2;
            int rl = (j & 3) * 16 + w * 4 + (lane >> 4);
            int oct = slot ^ ((rl >> 1) & 3);
            const unsigned* s32 = (const unsigned*)(plane ? &HQ[rl][kb2 * 32 + oct * 8]
                                                          : &HV[rl][kb2 * 32 + oct * 8]);
            uint4 vst = make_uint4(s32[0], s32[1], s32[2], s32[3]);
            unsigned short* dst = (plane ? Gq : Gv)
                + (size_t)(r0 + rl) * 256 + (h * 4 + kb2) * 32 + slot * 8;
            *(uint4*)dst = vst;
        }
        __syncthreads();
    }
}

// ---------------------------------------------------------------- GEMM1 (MFMA)
// 256x128 tile, 512 threads (8 waves, 4x2), double-buffered A+B in LDS (48 KB),
// XCD swizzle. (B-direct variant regressed: L2-latency-serialized K-loop.)
__global__ __launch_bounds__(512, 4) void gemm1_mfma(
    const unsigned short* __restrict__ Gv, const unsigned short* __restrict__ Gq,
    const unsigned short* __restrict__ W1hi, const unsigned short* __restrict__ W1lo,
    const float* __restrict__ bv, const float* __restrict__ battn, const float* __restrict__ bbox,
    unsigned short* __restrict__ VPb, float* __restrict__ LB) {
    __shared__ __align__(16) unsigned short Ah[2][8192], Bh[2][4096], Bl[2][4096];
    int t = threadIdx.x;
    int lid = xcd_swz(blockIdx.x, 4 * (RPAD / 256));   // 832 blocks
    int nb = lid & 3;                    // 0..3
    int r0 = (lid >> 2) * 256;
    const unsigned short* Asrc = (nb < 2) ? Gv : Gq;
    int w = t >> 6, lane = t & 63;
    int wr = w >> 1, wc = w & 1;         // 4x2 wave grid
    int row_l = lane & 15, oct = lane >> 4;

    const unsigned short* Bbh = W1hi + (size_t)nb * 32768;
    const unsigned short* Bbl = W1lo + (size_t)nb * 32768;

    f4 acc[4][4];
    #pragma unroll
    for (int i = 0; i < 4; ++i)
        #pragma unroll
        for (int j = 0; j < 4; ++j) acc[i][j] = (f4){0.f, 0.f, 0.f, 0.f};

    int c0 = t, c1 = t + 512;
    const unsigned short* a0b = Asrc + (size_t)(r0 + (c0 >> 2)) * 256 + (c0 & 3) * 8;
    const unsigned short* a1b = Asrc + (size_t)(r0 + (c1 >> 2)) * 256 + (c1 & 3) * 8;

#define G1_STAGE(bb, kb)                                                            \
    {                                                                               \
        __builtin_amdgcn_global_load_lds(a0b + (kb) * 32, &Ah[bb][w * 512], 16, 0, 0);        \
        __builtin_amdgcn_global_load_lds(a1b + (kb) * 32, &Ah[bb][4096 + w * 512], 16, 0, 0); \
        __builtin_amdgcn_global_load_lds(Bbh + (kb) * 4096 + c0 * 8, &Bh[bb][w * 512], 16, 0, 0); \
        __builtin_amdgcn_global_load_lds(Bbl + (kb) * 4096 + c0 * 8, &Bl[bb][w * 512], 16, 0, 0); \
    }

    G1_STAGE(0, 0);
    for (int kb = 0; kb < 8; ++kb) {
        __syncthreads();                       // drains prefetch; buf kb ready
        if (kb < 7) G1_STAGE((kb + 1) & 1, kb + 1);
        int bb = kb & 1;
        bf8 a[4], bh[4], bl[4];
        #pragma unroll
        for (int x = 0; x < 4; ++x) {
            int ri = wr * 64 + x * 16 + row_l;     // 0..255
            int ci = wc * 64 + x * 16 + row_l;     // 0..127
            a[x]  = *(const bf8*)(&Ah[bb][ri * 32 + swzf(ri, oct) * 8]);
            bh[x] = *(const bf8*)(&Bh[bb][ci * 32 + swzf(ci, oct) * 8]);
            bl[x] = *(const bf8*)(&Bl[bb][ci * 32 + swzf(ci, oct) * 8]);
        }
        #pragma unroll
        for (int mi = 0; mi < 4; ++mi)
            #pragma unroll
            for (int ni = 0; ni < 4; ++ni) {
                f4 c = acc[mi][ni];
                c = __builtin_amdgcn_mfma_f32_16x16x32_bf16(a[mi], bh[ni], c, 0, 0, 0);
                c = __builtin_amdgcn_mfma_f32_16x16x32_bf16(a[mi], bl[ni], c, 0, 0, 0);
                acc[mi][ni] = c;
            }
    }
    #pragma unroll
    for (int ni = 0; ni < 4; ++ni) {
        int col = wc * 64 + ni * 16 + row_l;
        float bias;
        if (nb == 0) bias = bv[col];
        else if (nb == 1) bias = bv[128 + col];
        else if (nb == 2) bias = battn[col];
        else bias = bbox[col];
        #pragma unroll
        for (int mi = 0; mi < 4; ++mi) {
            #pragma unroll
            for (int v = 0; v < 4; ++v) {
                int rr = r0 + wr * 64 + mi * 16 + oct * 4 + v;
                if (rr < BTOT) {
                    float val = acc[mi][ni][v] + bias;
                    if (nb < 2) VPb[(size_t)rr * 256 + nb * 128 + col] = f2bf(val);
                    else        LB[(size_t)rr * 256 + (nb - 2) * 128 + col] = val;
                }
            }
        }
    }
}

// ---------------------------------------------------------------- sampler v12
// 256 thr = 64 groups, 4 lanes/group (lane = level). Register-resident phase 1,
// width-4 shuffle broadcast phase 2, dwordx4 bf16 gathers + packed f32 fma.
__global__ __launch_bounds__(256) void sampler_kernel(const unsigned short* __restrict__ VPb,
                                                      const float* __restrict__ LB,
                                                      const float4* __restrict__ geot,
                                                      unsigned short* __restrict__ att_hi,
                                                      unsigned short* __restrict__ att_lo) {
    int t = threadIdx.x;
    int blk = xcd_swz(blockIdx.x, (BTOT * NH) / 64);   // 6647 blocks
    int gidx = t >> 2, lane4 = t & 3;                  // lane4 = level
    int grp = blk * 64 + gidx;
    int m = grp & 7, r = grp >> 3;

    float4 gt = geot[r];
    float cx = gt.x, cy = gt.y, rsw = gt.z;
    int rb0 = __float_as_int(gt.w);

    const float* Lrow = LB + (size_t)r * 256;
    float4 lg4 = *(const float4*)&Lrow[m * 16 + lane4 * 4];
    float4 ob  = *(const float4*)&Lrow[128 + m * 16 + lane4 * 4];

    float mx = fmaxf(fmaxf(lg4.x, lg4.y), fmaxf(lg4.z, lg4.w));
    mx = fmaxf(mx, __shfl_xor(mx, 1, 4));
    mx = fmaxf(mx, __shfl_xor(mx, 2, 4));
    float e0 = __expf(lg4.x - mx), e1 = __expf(lg4.y - mx);
    float e2 = __expf(lg4.z - mx), e3 = __expf(lg4.w - mx);
    float s = (e0 + e1) + (e2 + e3);
    s += __shfl_xor(s, 1, 4);
    s += __shfl_xor(s, 2, 4);
    float inv = 1.0f / s;

    float fW2 = lane4 == 0 ? 100.f : lane4 == 1 ? 50.f : lane4 == 2 ? 25.f : 13.f;
    int   W2i = lane4 == 0 ? 100   : lane4 == 1 ? 50   : lane4 == 2 ? 25   : 13;
    int  rowb = rb0 + (lane4 == 0 ? 0 : lane4 == 1 ? 10000 : lane4 == 2 ? 12500 : 13125);
    int  col  = m * 32;

    float bcx = cx + ob.x * 0.125f * rsw;
    float bcy = cy + ob.y * 0.125f * rsw;
    float bsx = fmaxf(fmaf(ob.z * 0.125f, rsw, rsw), 0.f);
    float bsy = fmaxf(fmaf(ob.w * 0.125f, rsw, rsw), 0.f);

    float4 wA[4]; int4 iA[4];
    float ev[4] = {e0, e1, e2, e3};
    #pragma unroll
    for (int pp = 0; pp < 4; ++pp) {
        float aw = ev[pp] * inv;
        float kx = (pp & 1)  ? 0.25f : -0.25f;
        float ky = (pp >> 1) ? 0.25f : -0.25f;
        float xs = fmaf(bcx + kx * bsx, fW2, -0.5f);
        float ys = fmaf(bcy + ky * bsy, fW2, -0.5f);
        float x0f = floorf(xs), y0f = floorf(ys);
        float lx = xs - x0f, ly = ys - y0f;
        int x0 = (int)x0f, y0 = (int)y0f;
        int x1 = x0 + 1, y1 = y0 + 1;
        bool vx0 = (x0 >= 0) & (x0 < W2i), vx1 = (x1 >= 0) & (x1 < W2i);
        bool vy0 = (y0 >= 0) & (y0 < W2i), vy1 = (y1 >= 0) & (y1 < W2i);
        int x0c = min(max(x0, 0), W2i - 1), x1c = min(max(x1, 0), W2i - 1);
        int y0c = min(max(y0, 0), W2i - 1), y1c = min(max(y1, 0), W2i - 1);
        wA[pp].x = (vx0 & vy0) ? aw * (1.f - lx) * (1.f - ly) : 0.f;
        wA[pp].y = (vx1 & vy0) ? aw * lx * (1.f - ly) : 0.f;
        wA[pp].z = (vx0 & vy1) ? aw * (1.f - lx) * ly : 0.f;
        wA[pp].w = (vx1 & vy1) ? aw * lx * ly : 0.f;
        iA[pp].x = ((rowb + y0c * W2i + x0c) * 256 + col) * 2;   // BYTE offsets
        iA[pp].y = ((rowb + y0c * W2i + x1c) * 256 + col) * 2;
        iA[pp].z = ((rowb + y1c * W2i + x0c) * 256 + col) * 2;
        iA[pp].w = ((rowb + y1c * W2i + x1c) * 256 + col) * 2;
    }

    unsigned dby = (unsigned)lane4 * 16u;          // 8 channels x 2B
    const char* Vb = (const char*)VPb;
    f2 a01 = {0.f, 0.f}, a23 = {0.f, 0.f}, a45 = {0.f, 0.f}, a67 = {0.f, 0.f};

#define PSTEP(P)                                                                      \
    {                                                                                 \
        float w00 = __shfl(wA[(P) & 3].x, (P) >> 2, 4);                               \
        float w01 = __shfl(wA[(P) & 3].y, (P) >> 2, 4);                               \
        float w10 = __shfl(wA[(P) & 3].z, (P) >> 2, 4);                               \
        float w11 = __shfl(wA[(P) & 3].w, (P) >> 2, 4);                               \
        unsigned o00 = (unsigned)__shfl(iA[(P) & 3].x, (P) >> 2, 4) + dby;            \
        unsigned o01 = (unsigned)__shfl(iA[(P) & 3].y, (P) >> 2, 4) + dby;            \
        unsigned o10 = (unsigned)__shfl(iA[(P) & 3].z, (P) >> 2, 4) + dby;            \
        unsigned o11 = (unsigned)__shfl(iA[(P) & 3].w, (P) >> 2, 4) + dby;            \
        uint4 u00 = *(const uint4*)(Vb + (size_t)o00);                                \
        uint4 u01 = *(const uint4*)(Vb + (size_t)o01);                                \
        uint4 u10 = *(const uint4*)(Vb + (size_t)o10);                                \
        uint4 u11 = *(const uint4*)(Vb + (size_t)o11);                                \
        f2 ww0 = {w00, w00}, ww1 = {w01, w01}, ww2 = {w10, w10}, ww3 = {w11, w11};    \
        a01 = __builtin_elementwise_fma(ww0, up2(u00.x), a01);                        \
        a23 = __builtin_elementwise_fma(ww0, up2(u00.y), a23);                        \
        a45 = __builtin_elementwise_fma(ww0, up2(u00.z), a45);                        \
        a67 = __builtin_elementwise_fma(ww0, up2(u00.w), a67);                        \
        a01 = __builtin_elementwise_fma(ww1, up2(u01.x), a01);                        \
        a23 = __builtin_elementwise_fma(ww1, up2(u01.y), a23);                        \
        a45 = __builtin_elementwise_fma(ww1, up2(u01.z), a45);                        \
        a67 = __builtin_elementwise_fma(ww1, up2(u01.w), a67);                        \
        a01 = __builtin_elementwise_fma(ww2, up2(u10.x), a01);                        \
        a23 = __builtin_elementwise_fma(ww2, up2(u10.y), a23);                        \
        a45 = __builtin_elementwise_fma(ww2, up2(u10.z), a45);                        \
        a67 = __builtin_elementwise_fma(ww2, up2(u10.w), a67);                        \
        a01 = __builtin_elementwise_fma(ww3, up2(u11.x), a01);                        \
        a23 = __builtin_elementwise_fma(ww3, up2(u11.y), a23);                        \
        a45 = __builtin_elementwise_fma(ww3, up2(u11.z), a45);                        \
        a67 = __builtin_elementwise_fma(ww3, up2(u11.w), a67);                        \
    }

    PSTEP(0)  PSTEP(1)  PSTEP(2)  PSTEP(3)
    PSTEP(4)  PSTEP(5)  PSTEP(6)  PSTEP(7)
    PSTEP(8)  PSTEP(9)  PSTEP(10) PSTEP(11)
    PSTEP(12) PSTEP(13) PSTEP(14) PSTEP(15)
#undef PSTEP

    // 8 channels = one full octet; baked swizzle for GEMM2 A staging
    int slot = lane4 ^ ((r >> 1) & 3);
    size_t base = (size_t)r * 256 + m * 32 + slot * 8;
    float av[8] = {a01.x, a01.y, a23.x, a23.y, a45.x, a45.y, a67.x, a67.y};
    unsigned hp[4], lp4[4];
    #pragma unroll
    for (int q = 0; q < 4; ++q) {
        unsigned short h0 = f2bf(av[q * 2]), h1 = f2bf(av[q * 2 + 1]);
        unsigned short l0 = f2bf(av[q * 2] - bf2f(h0)), l1 = f2bf(av[q * 2 + 1] - bf2f(h1));
        hp[q]  = ((unsigned)h1 << 16) | h0;
        lp4[q] = ((unsigned)l1 << 16) | l0;
    }
    *(uint4*)&att_hi[base] = make_uint4(hp[0], hp[1], hp[2], hp[3]);
    *(uint4*)&att_lo[base] = make_uint4(lp4[0], lp4[1], lp4[2], lp4[3]);
}

// ---------------------------------------------------------------- GEMM2 (MFMA)
// 256x128 tile, 512 threads (8 waves, 4x2), double-buffered A+B in LDS (96 KB),
// XCD swizzle.
__global__ __launch_bounds__(512, 2) void gemm2_mfma(
    const unsigned short* __restrict__ Ahi_g, const unsigned short* __restrict__ Alo_g,
    const unsigned short* __restrict__ Wohi, const unsigned short* __restrict__ Wolo,
    const float* __restrict__ bo, float* __restrict__ out) {
    __shared__ __align__(16) unsigned short Ah[2][8192], Al[2][8192], Bh[2][4096], Bl[2][4096];
    int t = threadIdx.x;
    int lid = xcd_swz(blockIdx.x, 2 * (RPAD / 256));   // 416 blocks
    int nb = lid & 1;                    // 0..1
    int r0 = (lid >> 1) * 256;
    int w = t >> 6, lane = t & 63;
    int wr = w >> 1, wc = w & 1;         // 4x2 wave grid
    int row_l = lane & 15, oct = lane >> 4;

    const unsigned short* Bbh = Wohi + (size_t)nb * 32768;
    const unsigned short* Bbl = Wolo + (size_t)nb * 32768;

    f4 acc[4][4];
    #pragma unroll
    for (int i = 0; i < 4; ++i)
        #pragma unroll
        for (int j = 0; j < 4; ++j) acc[i][j] = (f4){0.f, 0.f, 0.f, 0.f};

    int c0 = t, c1 = t + 512;
    int ra0 = r0 + (c0 >> 2); if (ra0 >= BTOT) ra0 = BTOT - 1;
    int ra1 = r0 + (c1 >> 2); if (ra1 >= BTOT) ra1 = BTOT - 1;
    const unsigned short* ah0 = Ahi_g + (size_t)ra0 * 256 + (c0 & 3) * 8;
    const unsigned short* ah1 = Ahi_g + (size_t)ra1 * 256 + (c1 & 3) * 8;
    const unsigned short* al0 = Alo_g + (size_t)ra0 * 256 + (c0 & 3) * 8;
    const unsigned short* al1 = Alo_g + (size_t)ra1 * 256 + (c1 & 3) * 8;

#define G2_STAGE(bb, kb)                                                            \
    {                                                                               \
        __builtin_amdgcn_global_load_lds(ah0 + (kb) * 32, &Ah[bb][w * 512], 16, 0, 0);        \
        __builtin_amdgcn_global_load_lds(ah1 + (kb) * 32, &Ah[bb][4096 + w * 512], 16, 0, 0); \
        __builtin_amdgcn_global_load_lds(al0 + (kb) * 32, &Al[bb][w * 512], 16, 0, 0);        \
        __builtin_amdgcn_global_load_lds(al1 + (kb) * 32, &Al[bb][4096 + w * 512], 16, 0, 0); \
        __builtin_amdgcn_global_load_lds(Bbh + (kb) * 4096 + c0 * 8, &Bh[bb][w * 512], 16, 0, 0); \
        __builtin_amdgcn_global_load_lds(Bbl + (kb) * 4096 + c0 * 8, &Bl[bb][w * 512], 16, 0, 0); \
    }

    G2_STAGE(0, 0);
    for (int kb = 0; kb < 8; ++kb) {
        __syncthreads();
        if (kb < 7) G2_STAGE((kb + 1) & 1, kb + 1);
        int bb = kb & 1;
        bf8 ah[4], al[4], bh[4], bl[4];
        #pragma unroll
        for (int x = 0; x < 4; ++x) {
            int ri = wr * 64 + x * 16 + row_l;     // 0..255
            int ci = wc * 64 + x * 16 + row_l;     // 0..127
            ah[x] = *(const bf8*)(&Ah[bb][ri * 32 + swzf(ri, oct) * 8]);
            al[x] = *(const bf8*)(&Al[bb][ri * 32 + swzf(ri, oct) * 8]);
            bh[x] = *(const bf8*)(&Bh[bb][ci * 32 + swzf(ci, oct) * 8]);
            bl[x] = *(const bf8*)(&Bl[bb][ci * 32 + swzf(ci, oct) * 8]);
        }
        #pragma unroll
        for (int mi = 0; mi < 4; ++mi)
            #pragma unroll
            for (int ni = 0; ni < 4; ++ni) {
                f4 c = acc[mi][ni];
                c = __builtin_amdgcn_mfma_f32_16x16x32_bf16(ah[mi], bh[ni], c, 0, 0, 0);
                c = __builtin_amdgcn_mfma_f32_16x16x32_bf16(ah[mi], bl[ni], c, 0, 0, 0);
                c = __builtin_amdgcn_mfma_f32_16x16x32_bf16(al[mi], bh[ni], c, 0, 0, 0);
                acc[mi][ni] = c;
            }
    }
    #pragma unroll
    for (int ni = 0; ni < 4; ++ni) {
        int col = wc * 64 + ni * 16 + row_l;
        float bias = bo[nb * 128 + col];
        #pragma unroll
        for (int mi = 0; mi < 4; ++mi) {
            #pragma unroll
            for (int v = 0; v < 4; ++v) {
                int rr = r0 + wr * 64 + mi * 16 + oct * 4 + v;
                if (rr < BTOT)
                    out[(size_t)rr * 256 + nb * 128 + col] = acc[mi][ni][v] + bias;
            }
        }
    }
}

// ---------------------------------------------------------------- launch
extern "C" void kernel_launch(void* const* d_in, const int* in_sizes, int n_in,
                              void* d_out, int out_size, void* d_ws, size_t ws_size,
                              hipStream_t stream) {
    const float* v0 = (const float*)d_in[0];
    const float* p0 = (const float*)d_in[1];
    const float* v1 = (const float*)d_in[2];
    const float* p1 = (const float*)d_in[3];
    const float* v2 = (const float*)d_in[4];
    const float* p2 = (const float*)d_in[5];
    const float* v3 = (const float*)d_in[6];
    const float* p3 = (const float*)d_in[7];
    const float* Wv    = (const float*)d_in[8];
    const float* bv    = (const float*)d_in[9];
    const float* Wo    = (const float*)d_in[10];
    const float* bo    = (const float*)d_in[11];
    const float* Wbox  = (const float*)d_in[12];
    const float* bbox  = (const float*)d_in[13];
    const float* Wattn = (const float*)d_in[14];
    const float* battn = (const float*)d_in[15];
    float* out = (float*)d_out;

    char* ws = (char*)d_ws;
    unsigned short* W1hi = (unsigned short*)(ws);                  // 256KB
    unsigned short* W1lo = (unsigned short*)(ws + 262144);         // 256KB
    unsigned short* Wohi = (unsigned short*)(ws + 524288);         // 128KB
    unsigned short* Wolo = (unsigned short*)(ws + 655360);         // 128KB
    // A panels (27.26MB each); atth/attl alias them (dead after gemm1)
    unsigned short* Gv   = (unsigned short*)(ws + 1048576);
    unsigned short* Gq   = (unsigned short*)(ws + 1048576 + 27262976);
    unsigned short* atth = Gv;
    unsigned short* attl = Gq;
    unsigned short* VPb  = (unsigned short*)(ws + 1048576 + 2 * 27262976);          // 27.23MB
    float*          LB   = (float*)(ws + 1048576 + 2 * 27262976 + 27226112);        // 54.45MB
    float4*         geot = (float4*)(ws + 1048576 + 2 * 27262976 + 27226112 + 54452224);  // 852KB

    convert_pack<<<dim3(NCONV + NPACK + NGEO), dim3(256), 0, stream>>>(
        v0, v1, v2, v3, p0, p1, p2, p3, Wv, Wattn, Wbox, Wo,
        Gv, Gq, W1hi, W1lo, Wohi, Wolo, geot);

    gemm1_mfma<<<dim3(4 * (RPAD / 256)), dim3(512), 0, stream>>>(
        Gv, Gq, W1hi, W1lo, bv, battn, bbox, VPb, LB);

    sampler_kernel<<<dim3((BTOT * NH) / 64), dim3(256), 0, stream>>>(VPb, LB, geot, atth, attl);

    gemm2_mfma<<<dim3(2 * (RPAD / 256)), dim3(512), 0, stream>>>(
        atth, attl, Wohi, Wolo, bo, out);
}